// Round 2
// baseline (14256.006 us; speedup 1.0000x reference)
//
#include <hip/hip_runtime.h>
#include <stdint.h>
#include <stddef.h>

typedef _Float16 half_t;
typedef __attribute__((ext_vector_type(8))) _Float16 halfx8;
typedef __attribute__((ext_vector_type(4))) float floatx4;

__device__ __forceinline__ float sigmoidf_(float x) { return 1.f / (1.f + __expf(-x)); }
__device__ __forceinline__ float tanhf_(float x) {
  x = fminf(fmaxf(x, -15.f), 15.f);
  float e = __expf(2.f * x);
  return (e - 1.f) / (e + 1.f);
}

__device__ __forceinline__ floatx4 mfma16(halfx8 a, halfx8 b, floatx4 c) {
  return __builtin_amdgcn_mfma_f32_16x16x32_f16(a, b, c, 0, 0, 0);
}

// ---------------- fp32 -> fp16 convert with optional row/col zero-pad ----------------
__global__ void convert_pad(const float* __restrict__ src, half_t* __restrict__ dst,
                            int srcRows, int srcCols, int dstRows, int dstCols) {
  int total = dstRows * dstCols;
  for (int i = blockIdx.x * blockDim.x + threadIdx.x; i < total; i += gridDim.x * blockDim.x) {
    int r = i / dstCols, c = i - r * dstCols;
    float v = (r < srcRows && c < srcCols) ? src[(size_t)r * srcCols + c] : 0.f;
    dst[i] = (half_t)v;
  }
}

// ---------------- GEMM: C(MxN,fp32) = relu(A(MxKa,fp32) * B(NxKp,fp16)^T + bias) ------
// Tile 128x128, BK=64, 4 waves (2x2), 16x16x32 f16 MFMA. A converted to fp16 at stage.
__global__ __launch_bounds__(256) void gemm_bias_relu(
    const float* __restrict__ A, int lda, int Ka,
    const half_t* __restrict__ B, int ldb,
    const float* __restrict__ bias,
    float* __restrict__ C, int N, int Kp) {
  __shared__ half_t As[128 * 64];
  __shared__ half_t Bs[128 * 64];
  const int t = threadIdx.x;
  const int w = t >> 6, l = t & 63;
  const int q = l >> 4, m15 = l & 15;
  const int rowBase = blockIdx.x * 128, colBase = blockIdx.y * 128;
  const int wm = (w >> 1) * 64, wn = (w & 1) * 64;
  const floatx4 z4 = {0.f, 0.f, 0.f, 0.f};
  floatx4 acc[4][4];
#pragma unroll
  for (int i = 0; i < 4; ++i)
#pragma unroll
    for (int j = 0; j < 4; ++j) acc[i][j] = z4;

  const int sr = t >> 3;         // 0..31
  const int sc = (t & 7) * 8;    // elem col offset 0..56

  for (int k0 = 0; k0 < Kp; k0 += 64) {
    __syncthreads();
    const bool full = (k0 + 64 <= Ka);
#pragma unroll
    for (int p = 0; p < 4; ++p) {
      const int r = p * 32 + sr;
      halfx8 tmp;
      if (full) {
        const float4* s0 = (const float4*)(A + (size_t)(rowBase + r) * lda + k0 + sc);
        float4 f0 = s0[0], f1 = s0[1];
        tmp[0] = (half_t)f0.x; tmp[1] = (half_t)f0.y; tmp[2] = (half_t)f0.z; tmp[3] = (half_t)f0.w;
        tmp[4] = (half_t)f1.x; tmp[5] = (half_t)f1.y; tmp[6] = (half_t)f1.z; tmp[7] = (half_t)f1.w;
      } else {
#pragma unroll
        for (int j2 = 0; j2 < 8; ++j2) {
          int kk = k0 + sc + j2;
          tmp[j2] = (half_t)(kk < Ka ? A[(size_t)(rowBase + r) * lda + kk] : 0.f);
        }
      }
      *(halfx8*)(&As[r * 64 + sc]) = tmp;
    }
#pragma unroll
    for (int p = 0; p < 4; ++p) {
      const int chunk = p * 256 + t;
      const int r = chunk >> 3, cc = (chunk & 7) * 8;
      *(halfx8*)(&Bs[r * 64 + cc]) =
          *(const halfx8*)(B + (size_t)(colBase + r) * ldb + k0 + cc);
    }
    __syncthreads();
#pragma unroll
    for (int kk = 0; kk < 2; ++kk) {
      const int ko = kk * 32 + q * 8;
      halfx8 af[4], bfr[4];
#pragma unroll
      for (int i = 0; i < 4; ++i) af[i] = *(const halfx8*)(&As[(wm + i * 16 + m15) * 64 + ko]);
#pragma unroll
      for (int j = 0; j < 4; ++j) bfr[j] = *(const halfx8*)(&Bs[(wn + j * 16 + m15) * 64 + ko]);
#pragma unroll
      for (int i = 0; i < 4; ++i)
#pragma unroll
        for (int j = 0; j < 4; ++j) acc[i][j] = mfma16(af[i], bfr[j], acc[i][j]);
    }
  }
#pragma unroll
  for (int j = 0; j < 4; ++j) {
    const int n = colBase + wn + j * 16 + m15;
    const float bv = bias[n];
#pragma unroll
    for (int i = 0; i < 4; ++i)
#pragma unroll
      for (int r = 0; r < 4; ++r) {
        const int m = rowBase + wm + i * 16 + q * 4 + r;
        C[(size_t)m * N + n] = fmaxf(acc[i][j][r] + bv, 0.f);
      }
  }
}

// ---------------- fused persistent GRU (2 layers) + FC + softmax ----------------
// 256 blocks x 256 thr (4 waves). Block owns 32 rows for all 128 steps.
// h kept in LDS (fp16, in-place update) + fp32 "hold" registers for the z*h term.
// Weights streamed global->VGPR frags each step (L2-resident, 1.57 MB total).
#define HLD 264  // padded LDS row stride (elements)

template <bool SKIPH>
__device__ __forceinline__ void gru_layer(
    const half_t* __restrict__ X, half_t* __restrict__ H,
    const half_t* __restrict__ wih, const half_t* __restrict__ whh,
    const float* __restrict__ bl, float (&hold)[2][4][4],
    const int w, const int q, const int m15) {
  const floatx4 z4 = {0.f, 0.f, 0.f, 0.f};
  halfx8 hfr[2][8];
  if (!SKIPH) {
#pragma unroll
    for (int mt = 0; mt < 2; ++mt)
#pragma unroll
      for (int ks = 0; ks < 8; ++ks)
        hfr[mt][ks] = *(const halfx8*)(&H[(mt * 16 + m15) * HLD + ks * 32 + q * 8]);
  }
  __syncthreads();  // all reads of old H done before in-place writes below
#pragma unroll
  for (int pair = 0; pair < 2; ++pair) {
    floatx4 ai[2][2][3], ah[2][2][3];
#pragma unroll
    for (int mt = 0; mt < 2; ++mt)
#pragma unroll
      for (int jj = 0; jj < 2; ++jj)
#pragma unroll
        for (int g = 0; g < 3; ++g) { ai[mt][jj][g] = z4; ah[mt][jj][g] = z4; }
#pragma unroll
    for (int ks = 0; ks < 8; ++ks) {
      const int ko = ks * 32 + q * 8;
      halfx8 xf[2];
#pragma unroll
      for (int mt = 0; mt < 2; ++mt)
        xf[mt] = *(const halfx8*)(&X[(mt * 16 + m15) * HLD + ko]);
#pragma unroll
      for (int jj = 0; jj < 2; ++jj) {
        const int n0 = ((w << 2) + (pair << 1) + jj) * 16 + m15;
#pragma unroll
        for (int g = 0; g < 3; ++g) {
          const int n = g * 256 + n0;
          const halfx8 wf = *(const halfx8*)(&wih[(size_t)n * 256 + ko]);
#pragma unroll
          for (int mt = 0; mt < 2; ++mt) ai[mt][jj][g] = mfma16(xf[mt], wf, ai[mt][jj][g]);
          if (!SKIPH) {
            const halfx8 wh = *(const halfx8*)(&whh[(size_t)n * 256 + ko]);
#pragma unroll
            for (int mt = 0; mt < 2; ++mt) ah[mt][jj][g] = mfma16(hfr[mt][ks], wh, ah[mt][jj][g]);
          }
        }
      }
    }
    // gates + in-place H update (C layout: col=lane&15, row=q*4+reg)
#pragma unroll
    for (int jj = 0; jj < 2; ++jj) {
      const int col = ((w << 2) + (pair << 1) + jj) * 16 + m15;
      const float br = bl[col], bz = bl[256 + col], bin = bl[512 + col], bhn = bl[768 + col];
#pragma unroll
      for (int mt = 0; mt < 2; ++mt)
#pragma unroll
        for (int r = 0; r < 4; ++r) {
          const float rr = sigmoidf_(ai[mt][jj][0][r] + ah[mt][jj][0][r] + br);
          const float zz = sigmoidf_(ai[mt][jj][1][r] + ah[mt][jj][1][r] + bz);
          const float nn = tanhf_(ai[mt][jj][2][r] + bin + rr * (ah[mt][jj][2][r] + bhn));
          float hv = hold[mt][(pair << 1) + jj][r];
          hv = (1.f - zz) * nn + zz * hv;
          hold[mt][(pair << 1) + jj][r] = hv;
          H[(mt * 16 + q * 4 + r) * HLD + col] = (half_t)hv;
        }
    }
  }
  __syncthreads();  // new H visible
}

__global__ __launch_bounds__(256, 1) void gru_fused(
    const float* __restrict__ e,
    const half_t* __restrict__ wih0, const half_t* __restrict__ whh0,
    const half_t* __restrict__ wih1, const half_t* __restrict__ whh1,
    const float* __restrict__ bih0, const float* __restrict__ bhh0,
    const float* __restrict__ bih1, const float* __restrict__ bhh1,
    const half_t* __restrict__ wfc, const float* __restrict__ bfc,
    float* __restrict__ out) {
  __shared__ half_t h0b[32 * HLD];
  __shared__ half_t h1b[32 * HLD];
  __shared__ float lg[32 * 48];
  __shared__ float bL[2][1024];  // [layer][{r_sum, z_sum, n_ih, n_hh} x 256]
  const int t = threadIdx.x;
  const int w = t >> 6, l = t & 63;
  const int q = l >> 4, m15 = l & 15;
  const int rowBase = blockIdx.x * 32;

  for (int i = t; i < 2048; i += 256) {
    const int layer = i >> 10, rem = i & 1023;
    const int which = rem >> 8, c = rem & 255;
    const float* bi = layer ? bih1 : bih0;
    const float* bh = layer ? bhh1 : bhh0;
    float v;
    if (which == 0) v = bi[c] + bh[c];
    else if (which == 1) v = bi[256 + c] + bh[256 + c];
    else if (which == 2) v = bi[512 + c];
    else v = bh[512 + c];
    bL[layer][rem] = v;
  }
  for (int i = t; i < 32 * 256; i += 256) {
    const int r = i >> 8, c = i & 255;
    h1b[r * HLD + c] = (half_t)e[(size_t)(rowBase + r) * 256 + c];  // xt(0) = encoder out
  }
  __syncthreads();

  float h0old[2][4][4] = {};
  float h1old[2][4][4] = {};

#pragma unroll 1
  for (int ts = 0; ts < 128; ++ts) {
    if (ts == 0) {
      gru_layer<true >(h1b, h0b, wih0, whh0, bL[0], h0old, w, q, m15);
      gru_layer<true >(h0b, h1b, wih1, whh1, bL[1], h1old, w, q, m15);
    } else {
      gru_layer<false>(h1b, h0b, wih0, whh0, bL[0], h0old, w, q, m15);
      gru_layer<false>(h0b, h1b, wih1, whh1, bL[1], h1old, w, q, m15);
    }
    // ---- FC: y = relu(h1 @ wfc^T + bfc), logits to LDS ----
    if (w < 3) {
      const floatx4 z4 = {0.f, 0.f, 0.f, 0.f};
      floatx4 acc[2] = {z4, z4};
#pragma unroll
      for (int ks = 0; ks < 8; ++ks) {
        const int ko = ks * 32 + q * 8;
        const halfx8 wf = *(const halfx8*)(&wfc[(w * 16 + m15) * 256 + ko]);
#pragma unroll
        for (int mt = 0; mt < 2; ++mt) {
          const halfx8 hf = *(const halfx8*)(&h1b[(mt * 16 + m15) * HLD + ko]);
          acc[mt] = mfma16(hf, wf, acc[mt]);
        }
      }
      const int col = w * 16 + m15;
      const float bv = (col < 42) ? bfc[col] : 0.f;
#pragma unroll
      for (int mt = 0; mt < 2; ++mt)
#pragma unroll
        for (int r = 0; r < 4; ++r) {
          const int m = mt * 16 + q * 4 + r;
          lg[m * 48 + col] = (col < 42) ? fmaxf(acc[mt][r] + bv, 0.f) : -1e30f;
        }
    }
    __syncthreads();
    // ---- softmax over 42 classes + store ----
    {
      const int row = t >> 3, s = t & 7;
      float v[6];
#pragma unroll
      for (int k2 = 0; k2 < 6; ++k2) v[k2] = lg[row * 48 + s + k2 * 8];
      float mx = v[0];
#pragma unroll
      for (int k2 = 1; k2 < 6; ++k2) mx = fmaxf(mx, v[k2]);
#pragma unroll
      for (int d = 1; d < 8; d <<= 1) mx = fmaxf(mx, __shfl_xor(mx, d, 8));
      float sm = 0.f;
#pragma unroll
      for (int k2 = 0; k2 < 6; ++k2) { v[k2] = __expf(v[k2] - mx); sm += v[k2]; }
#pragma unroll
      for (int d = 1; d < 8; d <<= 1) sm += __shfl_xor(sm, d, 8);
      const float inv = 1.f / sm;
      const size_t base = ((size_t)(rowBase + row) * 128 + ts) * 42;
#pragma unroll
      for (int k2 = 0; k2 < 6; ++k2) {
        const int col = s + k2 * 8;
        if (col < 42) out[base + col] = v[k2] * inv;
      }
    }
    // no trailing barrier needed: next writers of lg/h are >=2 barriers away
  }
}

// ---------------- host launch ----------------
static inline void conv(const float* s, half_t* d, int sr, int sc, int dr, int dc,
                        hipStream_t st) {
  int total = dr * dc;
  int blocks = (total + 255) / 256;
  if (blocks > 4096) blocks = 4096;
  convert_pad<<<blocks, 256, 0, st>>>(s, d, sr, sc, dr, dc);
}

extern "C" void kernel_launch(void* const* d_in, const int* in_sizes, int n_in,
                              void* d_out, int out_size, void* d_ws, size_t ws_size,
                              hipStream_t stream) {
  const float* x    = (const float*)d_in[0];
  const float* w1   = (const float*)d_in[1];
  const float* b1   = (const float*)d_in[2];
  const float* w2   = (const float*)d_in[3];
  const float* b2   = (const float*)d_in[4];
  const float* w3   = (const float*)d_in[5];
  const float* b3   = (const float*)d_in[6];
  const float* w4   = (const float*)d_in[7];
  const float* b4   = (const float*)d_in[8];
  const float* wih0 = (const float*)d_in[9];
  const float* whh0 = (const float*)d_in[10];
  const float* bih0 = (const float*)d_in[11];
  const float* bhh0 = (const float*)d_in[12];
  const float* wih1 = (const float*)d_in[13];
  const float* whh1 = (const float*)d_in[14];
  const float* bih1 = (const float*)d_in[15];
  const float* bhh1 = (const float*)d_in[16];
  const float* wfc  = (const float*)d_in[17];
  const float* bfc  = (const float*)d_in[18];

  char* p = (char*)d_ws;
  half_t* w1b  = (half_t*)p; p += (size_t)2048 * 4864 * 2;
  half_t* w2b  = (half_t*)p; p += (size_t)1024 * 2048 * 2;
  half_t* w3b  = (half_t*)p; p += (size_t)512 * 1024 * 2;
  half_t* w4b  = (half_t*)p; p += (size_t)256 * 512 * 2;
  half_t* wi0b = (half_t*)p; p += (size_t)768 * 256 * 2;
  half_t* wh0b = (half_t*)p; p += (size_t)768 * 256 * 2;
  half_t* wi1b = (half_t*)p; p += (size_t)768 * 256 * 2;
  half_t* wh1b = (half_t*)p; p += (size_t)768 * 256 * 2;
  half_t* wfcb = (half_t*)p; p += (size_t)48 * 256 * 2;
  float* e1 = (float*)p; p += (size_t)8192 * 2048 * 4;
  float* e2 = (float*)p; p += (size_t)8192 * 1024 * 4;
  float* e3 = (float*)p; p += (size_t)8192 * 512 * 4;
  float* e4 = (float*)p; p += (size_t)8192 * 256 * 4;

  conv(w1, w1b, 2048, 4860, 2048, 4864, stream);
  conv(w2, w2b, 1024, 2048, 1024, 2048, stream);
  conv(w3, w3b, 512, 1024, 512, 1024, stream);
  conv(w4, w4b, 256, 512, 256, 512, stream);
  conv(wih0, wi0b, 768, 256, 768, 256, stream);
  conv(whh0, wh0b, 768, 256, 768, 256, stream);
  conv(wih1, wi1b, 768, 256, 768, 256, stream);
  conv(whh1, wh1b, 768, 256, 768, 256, stream);
  conv(wfc, wfcb, 42, 256, 48, 256, stream);

  gemm_bias_relu<<<dim3(64, 16), 256, 0, stream>>>(x, 4860, 4860, w1b, 4864, b1, e1, 2048, 4864);
  gemm_bias_relu<<<dim3(64, 8),  256, 0, stream>>>(e1, 2048, 2048, w2b, 2048, b2, e2, 1024, 2048);
  gemm_bias_relu<<<dim3(64, 4),  256, 0, stream>>>(e2, 1024, 1024, w3b, 1024, b3, e3, 512, 1024);
  gemm_bias_relu<<<dim3(64, 2),  256, 0, stream>>>(e3, 512, 512, w4b, 512, b4, e4, 256, 512);

  gru_fused<<<256, 256, 0, stream>>>(e4, wi0b, wh0b, wi1b, wh1b,
                                     bih0, bhh0, bih1, bhh1, wfcb, bfc, (float*)d_out);
}

// Round 3
// 7700.851 us; speedup vs baseline: 1.8512x; 1.8512x over previous
//
#include <hip/hip_runtime.h>
#include <stdint.h>
#include <stddef.h>

typedef _Float16 half_t;
typedef __attribute__((ext_vector_type(8))) _Float16 halfx8;
typedef __attribute__((ext_vector_type(4))) float floatx4;

__device__ __forceinline__ float sigmoidf_(float x) { return 1.f / (1.f + __expf(-x)); }
__device__ __forceinline__ float tanhf_(float x) {
  x = fminf(fmaxf(x, -15.f), 15.f);
  float e = __expf(2.f * x);
  return (e - 1.f) / (e + 1.f);
}

__device__ __forceinline__ floatx4 mfma16(halfx8 a, halfx8 b, floatx4 c) {
  return __builtin_amdgcn_mfma_f32_16x16x32_f16(a, b, c, 0, 0, 0);
}

// ---------------- fp32 -> fp16 convert with optional row/col zero-pad ----------------
__global__ void convert_pad(const float* __restrict__ src, half_t* __restrict__ dst,
                            int srcRows, int srcCols, int dstRows, int dstCols) {
  int total = dstRows * dstCols;
  for (int i = blockIdx.x * blockDim.x + threadIdx.x; i < total; i += gridDim.x * blockDim.x) {
    int r = i / dstCols, c = i - r * dstCols;
    float v = (r < srcRows && c < srcCols) ? src[(size_t)r * srcCols + c] : 0.f;
    dst[i] = (half_t)v;
  }
}

// ---------------- repack W (rows x 256, fp32) into MFMA B-frag order -------------------
// dst[nt][ks][lane][j] = W[nt*16 + (lane&15)][ks*32 + (lane>>4)*8 + j], fp16.
// A wave reading dst + (nt*8+ks)*64*8 + lane*8 gets its B fragment via one
// fully coalesced 1KB global_load_dwordx4.
__global__ void repack_bfrag(const float* __restrict__ src, half_t* __restrict__ dst,
                             int ntCount, int srcRows) {
  int total = ntCount * 8 * 64 * 8;
  for (int i = blockIdx.x * blockDim.x + threadIdx.x; i < total; i += gridDim.x * blockDim.x) {
    int j = i & 7, lane = (i >> 3) & 63, ks = (i >> 9) & 7, nt = i >> 12;
    int q = lane >> 4, m15 = lane & 15;
    int row = nt * 16 + m15;
    int col = ks * 32 + q * 8 + j;
    float v = (row < srcRows) ? src[(size_t)row * 256 + col] : 0.f;
    dst[i] = (half_t)v;
  }
}

// ---------------- GEMM: C(MxN,fp32) = relu(A(MxKa,fp32) * B(NxKp,fp16)^T + bias) ------
__global__ __launch_bounds__(256) void gemm_bias_relu(
    const float* __restrict__ A, int lda, int Ka,
    const half_t* __restrict__ B, int ldb,
    const float* __restrict__ bias,
    float* __restrict__ C, int N, int Kp) {
  __shared__ half_t As[128 * 64];
  __shared__ half_t Bs[128 * 64];
  const int t = threadIdx.x;
  const int w = t >> 6, l = t & 63;
  const int q = l >> 4, m15 = l & 15;
  const int rowBase = blockIdx.x * 128, colBase = blockIdx.y * 128;
  const int wm = (w >> 1) * 64, wn = (w & 1) * 64;
  const floatx4 z4 = {0.f, 0.f, 0.f, 0.f};
  floatx4 acc[4][4];
#pragma unroll
  for (int i = 0; i < 4; ++i)
#pragma unroll
    for (int j = 0; j < 4; ++j) acc[i][j] = z4;

  const int sr = t >> 3;
  const int sc = (t & 7) * 8;

  for (int k0 = 0; k0 < Kp; k0 += 64) {
    __syncthreads();
    const bool full = (k0 + 64 <= Ka);
#pragma unroll
    for (int p = 0; p < 4; ++p) {
      const int r = p * 32 + sr;
      halfx8 tmp;
      if (full) {
        const float4* s0 = (const float4*)(A + (size_t)(rowBase + r) * lda + k0 + sc);
        float4 f0 = s0[0], f1 = s0[1];
        tmp[0] = (half_t)f0.x; tmp[1] = (half_t)f0.y; tmp[2] = (half_t)f0.z; tmp[3] = (half_t)f0.w;
        tmp[4] = (half_t)f1.x; tmp[5] = (half_t)f1.y; tmp[6] = (half_t)f1.z; tmp[7] = (half_t)f1.w;
      } else {
#pragma unroll
        for (int j2 = 0; j2 < 8; ++j2) {
          int kk = k0 + sc + j2;
          tmp[j2] = (half_t)(kk < Ka ? A[(size_t)(rowBase + r) * lda + kk] : 0.f);
        }
      }
      *(halfx8*)(&As[r * 64 + sc]) = tmp;
    }
#pragma unroll
    for (int p = 0; p < 4; ++p) {
      const int chunk = p * 256 + t;
      const int r = chunk >> 3, cc = (chunk & 7) * 8;
      *(halfx8*)(&Bs[r * 64 + cc]) =
          *(const halfx8*)(B + (size_t)(colBase + r) * ldb + k0 + cc);
    }
    __syncthreads();
#pragma unroll
    for (int kk = 0; kk < 2; ++kk) {
      const int ko = kk * 32 + q * 8;
      halfx8 af[4], bfr[4];
#pragma unroll
      for (int i = 0; i < 4; ++i) af[i] = *(const halfx8*)(&As[(wm + i * 16 + m15) * 64 + ko]);
#pragma unroll
      for (int j = 0; j < 4; ++j) bfr[j] = *(const halfx8*)(&Bs[(wn + j * 16 + m15) * 64 + ko]);
#pragma unroll
      for (int i = 0; i < 4; ++i)
#pragma unroll
        for (int j = 0; j < 4; ++j) acc[i][j] = mfma16(af[i], bfr[j], acc[i][j]);
    }
  }
#pragma unroll
  for (int j = 0; j < 4; ++j) {
    const int n = colBase + wn + j * 16 + m15;
    const float bv = bias[n];
#pragma unroll
    for (int i = 0; i < 4; ++i)
#pragma unroll
      for (int r = 0; r < 4; ++r) {
        const int m = rowBase + wm + i * 16 + q * 4 + r;
        C[(size_t)m * N + n] = fmaxf(acc[i][j][r] + bv, 0.f);
      }
  }
}

// ---------------- fused persistent GRU (2 layers) + FC + softmax ----------------
// 256 blocks x 1024 thr (16 waves). Block owns 32 batch rows for all 128 steps.
// Wave w owns gate-col tile [w*16, w*16+16) for all 3 gates of both matmuls:
//   acc = {r (ih+hh summed), z (summed), n_ih, n_hh} x 2 row-tiles = 8 floatx4.
// Weights pre-repacked to B-frag order -> coalesced 1KB loads, L2-resident.
// h triple-buffered in LDS (fp16); fp32 z*h passthrough in registers.
#define HLD 260  // padded LDS row stride in halves (130 dwords; 130%32=2 -> even bank spread)

template <bool SKIPH>
__device__ __forceinline__ void gru_layer(
    const half_t* __restrict__ X, const half_t* __restrict__ Hold, half_t* __restrict__ Hnew,
    const half_t* __restrict__ wip, const half_t* __restrict__ whp,  // repacked
    const float* __restrict__ bl, float (&hold)[2][4],
    const int w, const int q, const int m15, const int lane) {
  const floatx4 z4 = {0.f, 0.f, 0.f, 0.f};
  floatx4 accR[2] = {z4, z4}, accZ[2] = {z4, z4}, accNi[2] = {z4, z4}, accNh[2] = {z4, z4};
  // weight frag element offset: ((g*16 + w)*8 + ks)*64*8 + lane*8 ; g stride = 65536 elems
  const half_t* bi = wip + ((size_t)w * 8 * 64 + lane) * 8;
  const half_t* bh = whp + ((size_t)w * 8 * 64 + lane) * 8;
#pragma unroll
  for (int ks = 0; ks < 8; ++ks) {
    const int ko = ks * 32 + q * 8;
    const int fo = ks * 512;  // 64 lanes * 8 elems
    halfx8 x0 = *(const halfx8*)(&X[m15 * HLD + ko]);
    halfx8 x1 = *(const halfx8*)(&X[(16 + m15) * HLD + ko]);
    halfx8 wr = *(const halfx8*)(bi + fo);
    halfx8 wz = *(const halfx8*)(bi + 65536 + fo);
    halfx8 wn = *(const halfx8*)(bi + 131072 + fo);
    accR[0] = mfma16(x0, wr, accR[0]);  accR[1] = mfma16(x1, wr, accR[1]);
    accZ[0] = mfma16(x0, wz, accZ[0]);  accZ[1] = mfma16(x1, wz, accZ[1]);
    accNi[0] = mfma16(x0, wn, accNi[0]); accNi[1] = mfma16(x1, wn, accNi[1]);
    if (!SKIPH) {
      halfx8 h0 = *(const halfx8*)(&Hold[m15 * HLD + ko]);
      halfx8 h1 = *(const halfx8*)(&Hold[(16 + m15) * HLD + ko]);
      halfx8 vr = *(const halfx8*)(bh + fo);
      halfx8 vz = *(const halfx8*)(bh + 65536 + fo);
      halfx8 vn = *(const halfx8*)(bh + 131072 + fo);
      accR[0] = mfma16(h0, vr, accR[0]);  accR[1] = mfma16(h1, vr, accR[1]);
      accZ[0] = mfma16(h0, vz, accZ[0]);  accZ[1] = mfma16(h1, vz, accZ[1]);
      accNh[0] = mfma16(h0, vn, accNh[0]); accNh[1] = mfma16(h1, vn, accNh[1]);
    }
  }
  const int col = w * 16 + m15;
  const float br = bl[col], bz = bl[256 + col], bin = bl[512 + col], bhn = bl[768 + col];
#pragma unroll
  for (int mt = 0; mt < 2; ++mt)
#pragma unroll
    for (int r = 0; r < 4; ++r) {
      const float rr = sigmoidf_(accR[mt][r] + br);
      const float zz = sigmoidf_(accZ[mt][r] + bz);
      const float nn = tanhf_(accNi[mt][r] + bin + rr * (accNh[mt][r] + bhn));
      float hv = hold[mt][r];
      hv = (1.f - zz) * nn + zz * hv;
      hold[mt][r] = hv;
      Hnew[(mt * 16 + q * 4 + r) * HLD + col] = (half_t)hv;
    }
  __syncthreads();
}

__global__ __launch_bounds__(1024) void gru_fused(
    const float* __restrict__ e,
    const half_t* __restrict__ wih0, const half_t* __restrict__ whh0,
    const half_t* __restrict__ wih1, const half_t* __restrict__ whh1,
    const float* __restrict__ bih0, const float* __restrict__ bhh0,
    const float* __restrict__ bih1, const float* __restrict__ bhh1,
    const half_t* __restrict__ wfc, const float* __restrict__ bfc,
    float* __restrict__ out) {
  __shared__ half_t hbuf[3][32 * HLD];
  __shared__ float lg[32 * 48];
  __shared__ float bL[2][1024];  // [layer][{r_sum, z_sum, n_ih, n_hh} x 256]
  const int t = threadIdx.x;
  const int w = t >> 6, lane = t & 63;
  const int q = lane >> 4, m15 = lane & 15;
  const int rowBase = blockIdx.x * 32;

  for (int i = t; i < 2048; i += 1024) {
    const int layer = i >> 10, rem = i & 1023;
    const int which = rem >> 8, c = rem & 255;
    const float* bi = layer ? bih1 : bih0;
    const float* bh = layer ? bhh1 : bhh0;
    float v;
    if (which == 0) v = bi[c] + bh[c];
    else if (which == 1) v = bi[256 + c] + bh[256 + c];
    else if (which == 2) v = bi[512 + c];
    else v = bh[512 + c];
    bL[layer][rem] = v;
  }
  for (int i = t; i < 32 * 256; i += 1024) {
    const int r = i >> 8, c = i & 255;
    hbuf[0][r * HLD + c] = (half_t)e[(size_t)(rowBase + r) * 256 + c];  // xt(0)
  }
  __syncthreads();

  float h0old[2][4] = {};
  float h1old[2][4] = {};

  // rotating buffers: pX1 = h1_old (= x_t), pX0 = h0_old, pF = free
  half_t* pX1 = hbuf[0];
  half_t* pX0 = hbuf[1];
  half_t* pF  = hbuf[2];

#pragma unroll 1
  for (int ts = 0; ts < 128; ++ts) {
    if (ts == 0) {
      gru_layer<true >(pX1, pX0, pF,  wih0, whh0, bL[0], h0old, w, q, m15, lane);
      gru_layer<true >(pF,  pX1, pX0, wih1, whh1, bL[1], h1old, w, q, m15, lane);
    } else {
      gru_layer<false>(pX1, pX0, pF,  wih0, whh0, bL[0], h0old, w, q, m15, lane);
      gru_layer<false>(pF,  pX1, pX0, wih1, whh1, bL[1], h1old, w, q, m15, lane);
    }
    // h1_new now in pX0 buffer; h0_new in pF buffer.
    // ---- FC: y = relu(h1 @ wfc^T + bfc) -> lg ----
    if (w < 3) {
      const floatx4 z4 = {0.f, 0.f, 0.f, 0.f};
      floatx4 acc[2] = {z4, z4};
      const half_t* bw = wfc + ((size_t)w * 8 * 64 + lane) * 8;
#pragma unroll
      for (int ks = 0; ks < 8; ++ks) {
        const int ko = ks * 32 + q * 8;
        const halfx8 wf = *(const halfx8*)(bw + ks * 512);
#pragma unroll
        for (int mt = 0; mt < 2; ++mt) {
          const halfx8 hf = *(const halfx8*)(&pX0[(mt * 16 + m15) * HLD + ko]);
          acc[mt] = mfma16(hf, wf, acc[mt]);
        }
      }
      const int col = w * 16 + m15;
      const float bv = (col < 42) ? bfc[col] : 0.f;
#pragma unroll
      for (int mt = 0; mt < 2; ++mt)
#pragma unroll
        for (int r = 0; r < 4; ++r) {
          const int m = mt * 16 + q * 4 + r;
          lg[m * 48 + col] = (col < 42) ? fmaxf(acc[mt][r] + bv, 0.f) : -1e30f;
        }
    }
    __syncthreads();
    // ---- softmax over 42 classes + store (first 4 waves) ----
    if (t < 256) {
      const int row = t >> 3, s = t & 7;
      float v[6];
#pragma unroll
      for (int k2 = 0; k2 < 6; ++k2) v[k2] = lg[row * 48 + s + k2 * 8];
      float mx = v[0];
#pragma unroll
      for (int k2 = 1; k2 < 6; ++k2) mx = fmaxf(mx, v[k2]);
#pragma unroll
      for (int d = 1; d < 8; d <<= 1) mx = fmaxf(mx, __shfl_xor(mx, d, 8));
      float sm = 0.f;
#pragma unroll
      for (int k2 = 0; k2 < 6; ++k2) { v[k2] = __expf(v[k2] - mx); sm += v[k2]; }
#pragma unroll
      for (int d = 1; d < 8; d <<= 1) sm += __shfl_xor(sm, d, 8);
      const float inv = 1.f / sm;
      const size_t base = ((size_t)(rowBase + row) * 128 + ts) * 42;
#pragma unroll
      for (int k2 = 0; k2 < 6; ++k2) {
        const int col = s + k2 * 8;
        if (col < 42) out[base + col] = v[k2] * inv;
      }
    }
    // rotate: h1_old <- pX0 (h1_new), h0_old <- pF (h0_new), free <- pX1
    half_t* tmp = pX1; pX1 = pX0; pX0 = pF; pF = tmp;
    // no trailing barrier: next writes to lg / h-bufs are >=1 full barrier away
  }
}

// ---------------- host launch ----------------
static inline void conv(const float* s, half_t* d, int sr, int sc, int dr, int dc,
                        hipStream_t st) {
  int total = dr * dc;
  int blocks = (total + 255) / 256;
  if (blocks > 4096) blocks = 4096;
  convert_pad<<<blocks, 256, 0, st>>>(s, d, sr, sc, dr, dc);
}

static inline void repk(const float* s, half_t* d, int ntCount, int srcRows, hipStream_t st) {
  int total = ntCount * 8 * 64 * 8;
  int blocks = (total + 255) / 256;
  repack_bfrag<<<blocks, 256, 0, st>>>(s, d, ntCount, srcRows);
}

extern "C" void kernel_launch(void* const* d_in, const int* in_sizes, int n_in,
                              void* d_out, int out_size, void* d_ws, size_t ws_size,
                              hipStream_t stream) {
  const float* x    = (const float*)d_in[0];
  const float* w1   = (const float*)d_in[1];
  const float* b1   = (const float*)d_in[2];
  const float* w2   = (const float*)d_in[3];
  const float* b2   = (const float*)d_in[4];
  const float* w3   = (const float*)d_in[5];
  const float* b3   = (const float*)d_in[6];
  const float* w4   = (const float*)d_in[7];
  const float* b4   = (const float*)d_in[8];
  const float* wih0 = (const float*)d_in[9];
  const float* whh0 = (const float*)d_in[10];
  const float* bih0 = (const float*)d_in[11];
  const float* bhh0 = (const float*)d_in[12];
  const float* wih1 = (const float*)d_in[13];
  const float* whh1 = (const float*)d_in[14];
  const float* bih1 = (const float*)d_in[15];
  const float* bhh1 = (const float*)d_in[16];
  const float* wfc  = (const float*)d_in[17];
  const float* bfc  = (const float*)d_in[18];

  char* p = (char*)d_ws;
  half_t* w1b  = (half_t*)p; p += (size_t)2048 * 4864 * 2;
  half_t* w2b  = (half_t*)p; p += (size_t)1024 * 2048 * 2;
  half_t* w3b  = (half_t*)p; p += (size_t)512 * 1024 * 2;
  half_t* w4b  = (half_t*)p; p += (size_t)256 * 512 * 2;
  half_t* wi0b = (half_t*)p; p += (size_t)48 * 4096 * 2;   // repacked B-frag order
  half_t* wh0b = (half_t*)p; p += (size_t)48 * 4096 * 2;
  half_t* wi1b = (half_t*)p; p += (size_t)48 * 4096 * 2;
  half_t* wh1b = (half_t*)p; p += (size_t)48 * 4096 * 2;
  half_t* wfcb = (half_t*)p; p += (size_t)3 * 4096 * 2;
  float* e1 = (float*)p; p += (size_t)8192 * 2048 * 4;
  float* e2 = (float*)p; p += (size_t)8192 * 1024 * 4;
  float* e3 = (float*)p; p += (size_t)8192 * 512 * 4;
  float* e4 = (float*)p; p += (size_t)8192 * 256 * 4;

  conv(w1, w1b, 2048, 4860, 2048, 4864, stream);
  conv(w2, w2b, 1024, 2048, 1024, 2048, stream);
  conv(w3, w3b, 512, 1024, 512, 1024, stream);
  conv(w4, w4b, 256, 512, 256, 512, stream);
  repk(wih0, wi0b, 48, 768, stream);
  repk(whh0, wh0b, 48, 768, stream);
  repk(wih1, wi1b, 48, 768, stream);
  repk(whh1, wh1b, 48, 768, stream);
  repk(wfc, wfcb, 3, 42, stream);

  gemm_bias_relu<<<dim3(64, 16), 256, 0, stream>>>(x, 4860, 4860, w1b, 4864, b1, e1, 2048, 4864);
  gemm_bias_relu<<<dim3(64, 8),  256, 0, stream>>>(e1, 2048, 2048, w2b, 2048, b2, e2, 1024, 2048);
  gemm_bias_relu<<<dim3(64, 4),  256, 0, stream>>>(e2, 1024, 1024, w3b, 1024, b3, e3, 512, 1024);
  gemm_bias_relu<<<dim3(64, 2),  256, 0, stream>>>(e3, 512, 512, w4b, 512, b4, e4, 256, 512);

  gru_fused<<<256, 1024, 0, stream>>>(e4, wi0b, wh0b, wi1b, wh1b,
                                      bih0, bhh0, bih1, bhh1, wfcb, bfc, (float*)d_out);
}